// Round 6
// baseline (292.288 us; speedup 1.0000x reference)
//
#include <hip/hip_runtime.h>
#include <hip/hip_bf16.h>
#include <stdint.h>

using bf16 = __hip_bfloat16;
typedef __attribute__((ext_vector_type(8))) short bf16x8;
typedef __attribute__((ext_vector_type(4))) float f32x4;

#define BATCHN 512

// ---------------- gating + leaf probs ----------------
__global__ void gate_kernel(const float* __restrict__ x, const float* __restrict__ gw,
                            const float* __restrict__ gb, float* __restrict__ lp) {
  __shared__ float xs[128];
  __shared__ float gs[32];
  const int b = blockIdx.x;
  const int t = threadIdx.x; // 0..63
  xs[t] = x[b*128 + t];
  xs[t + 64] = x[b*128 + 64 + t];
  __syncthreads();
  if (t < 31) {
    float acc = gb[t];
    #pragma unroll 8
    for (int k = 0; k < 128; ++k) acc += xs[k] * gw[k*31 + t];
    gs[t] = 1.f / (1.f + __expf(-acc));
  }
  __syncthreads();
  if (t < 32) {
    float prob = 1.f;
    #pragma unroll
    for (int d = 1; d <= 5; ++d) {
      int i = t >> (6 - d);
      int node = (1 << (d - 1)) - 1 + i;
      float gv = gs[node];
      prob *= ((t >> (5 - d)) & 1) ? (1.f - gv) : gv;
    }
    lp[b*32 + t] = prob;
  }
}

// ---------------- mixture: out0 = lp @ z.T, written NHWC bf16 into x1 halo ----------------
__global__ void mixture_kernel(const float* __restrict__ z, const float* __restrict__ lp,
                               bf16* __restrict__ x1) {
  __shared__ float lps[64 * 32];
  const int s = blockIdx.x;          // h*8+w
  const int h = s >> 3, w = s & 7;
  const int b0 = blockIdx.y * 64;
  const int t = threadIdx.x;
  const int c = t & 127;
  const int half = t >> 7;
  float4 zr[8];
  const float4* zp = (const float4*)(z + (size_t)(c * 64 + s) * 32);
  #pragma unroll
  for (int i = 0; i < 8; ++i) zr[i] = zp[i];
  #pragma unroll
  for (int i = 0; i < 8; ++i) lps[t + 256 * i] = lp[b0 * 32 + t + 256 * i];
  __syncthreads();
  for (int bs = 0; bs < 32; ++bs) {
    int bl = half * 32 + bs;
    const float4* lr = (const float4*)(lps + bl * 32);
    float acc = 0.f;
    #pragma unroll
    for (int i = 0; i < 8; ++i) {
      float4 l4 = lr[i];
      acc += zr[i].x * l4.x + zr[i].y * l4.y + zr[i].z * l4.z + zr[i].w * l4.w;
    }
    int b = b0 + bl;
    x1[((size_t)(b * 10 + h + 1) * 10 + (w + 1)) * 128 + c] = __float2bfloat16(acc);
  }
}

// ---------------- zero the 1-px halo border of [512][H+2][W+2][C] bf16 ----------------
__global__ void zero_halo(bf16* __restrict__ buf, int H, int W, int C) {
  int idx = blockIdx.x * 256 + threadIdx.x;
  int nvec = C >> 3;
  int P = 2 * (W + 2) + 2 * H;
  int total = BATCHN * P * nvec;
  if (idx >= total) return;
  int cv = idx % nvec;
  int p = (idx / nvec) % P;
  int b = idx / (nvec * P);
  int row, col;
  if (p < W + 2) { row = 0; col = p; }
  else if (p < 2 * (W + 2)) { row = H + 1; col = p - (W + 2); }
  else { int q = p - 2 * (W + 2); row = 1 + (q >> 1); col = (q & 1) ? (W + 1) : 0; }
  float4 z4 = {0.f, 0.f, 0.f, 0.f};
  *(float4*)(buf + ((size_t)(b * (H + 2) + row) * (W + 2) + col) * C + cv * 8) = z4;
}

// ---------------- weight prep ----------------
// Layout: gB[chunk=(p*4+tap)][c][q][oc(OCp)][e=0..7], ic = c*32+q*8+e.
// One global_load_dwordx4 at lane li=oc yields the exact MFMA B fragment.
__global__ void wprep_kernel(const float* __restrict__ w, bf16* __restrict__ wt,
                             int IC, int OCr, int OCp) {
  int idx = blockIdx.x * 256 + threadIdx.x;
  int NC = IC / 32;
  int total = 16 * OCp * IC;
  if (idx >= total) return;
  int e = idx & 7;
  int t = idx >> 3;
  int oc = t % OCp; t /= OCp;
  int q = t & 3; t >>= 2;
  int c = t % NC; t /= NC;
  int tap = t & 3, p = t >> 2;
  int ic = c * 32 + q * 8 + e;
  int dy = tap >> 1, dx = tap & 1;
  int py = p >> 1, px = p & 1;
  const int ktab[2][2] = {{1, 3}, {2, 0}};
  int ky = ktab[py][dy], kx = ktab[px][dx];
  float v = 0.f;
  if (oc < OCr) v = w[((ic * OCr + oc) * 4 + ky) * 4 + kx];
  wt[idx] = __float2bfloat16(v);
}

// ---------------- barrier-free parity-fused transposed conv ----------------
// A: spatial tile staged ONCE into LDS (read-only after one barrier).
// B: fragments loaded global->VGPR (wt is L2-resident), ping-pong prefetched one
//    chunk ahead. No barriers in the K-loop; compiler inserts fine-grained vmcnt
//    waits since register-load deps are visible to it.
template<int IC, int OCp, int OCr, int IH, int IW, int ROWS, int BN,
         int WAVES_M, int WAVES_N, int MI, int NI, int MINW, bool RELU, bool FINAL>
__global__ __launch_bounds__(256, MINW)
void convt_reg(const bf16* __restrict__ xin, const bf16* __restrict__ wt,
               const float* __restrict__ bias, bf16* __restrict__ xout,
               float* __restrict__ fout) {
  constexpr int NC = IC / 32;
  constexpr int PLANES = NC * 4;
  constexpr int IH2 = IH + 2, IW2 = IW + 2;
  constexpr int OH2 = 2 * IH + 2, OW2 = 2 * IW + 2;
  constexpr int NPIX = (ROWS + 2) * IW2;
  constexpr int BPI = IH / ROWS;
  constexpr int WM = MI * 16, WN = NI * 16;
  constexpr int LIW = (IW == 8 ? 3 : (IW == 16 ? 4 : 5));
  constexpr int ICV = IC / 8;
  __shared__ bf16 Alds[PLANES * NPIX * 8];

  const int tid = threadIdx.x;
  const int wave = tid >> 6, lane = tid & 63;
  const int q = lane >> 4, li = lane & 15;
  const int wm = wave / WAVES_N, wn = wave % WAVES_N;
  const int img = blockIdx.x / BPI;
  const int tb = blockIdx.x % BPI;
  const int n0 = blockIdx.y * BN;

  // ---- stage A tile: global [pix][ic] -> LDS [plane=c*4+q][pix][8] ----
  const bf16* src = xin + ((size_t)img * IH2 + tb * ROWS) * IW2 * IC;
  for (int g = tid; g < NPIX * ICV; g += 256) {
    const int pix = g / ICV;
    const int gr = g % ICV;
    const float4 v = *(const float4*)(src + (size_t)g * 8);
    *(float4*)(&Alds[(gr * NPIX + pix) * 8]) = v;
  }

  // per-lane B base pointer: column = n0 + wn*WN + li (+ nj*16 in offset)
  const bf16* wtp = wt + (size_t)(n0 + wn * WN + li) * 8;

  // per-mi center pixel (lane li = m-row within 16)
  int cpix[MI];
  #pragma unroll
  for (int mi = 0; mi < MI; ++mi) {
    const int m = wm * WM + mi * 16 + li;
    cpix[mi] = ((m >> LIW) + 1) * IW2 + (m & (IW - 1)) + 1;
  }

  f32x4 acc[4][MI][NI];
  #pragma unroll
  for (int p = 0; p < 4; ++p)
    #pragma unroll
    for (int mi = 0; mi < MI; ++mi)
      #pragma unroll
      for (int nj = 0; nj < NI; ++nj)
        acc[p][mi][nj] = (f32x4){0.f, 0.f, 0.f, 0.f};

  bf16x8 b0[NC][NI], b1[NC][NI];

  auto loadB = [&](int chunk, bf16x8 (&bfr)[NC][NI]) {
    #pragma unroll
    for (int c = 0; c < NC; ++c)
      #pragma unroll
      for (int nj = 0; nj < NI; ++nj)
        bfr[c][nj] = *(const bf16x8*)(wtp + ((size_t)(chunk * PLANES + c * 4 + q) * OCp + nj * 16) * 8);
  };
  auto compute = [&](int chunk, bf16x8 (&bfr)[NC][NI]) {
    const int p = chunk >> 2, tap = chunk & 3;
    const int py = p >> 1, px = p & 1;
    const int sh = ((tap >> 1) ? (py ? 1 : -1) * IW2 : 0) + ((tap & 1) ? (px ? 1 : -1) : 0);
    #pragma unroll
    for (int c = 0; c < NC; ++c) {
      #pragma unroll
      for (int mi = 0; mi < MI; ++mi) {
        const bf16x8 a = *(const bf16x8*)(Alds + ((c * 4 + q) * NPIX + cpix[mi] + sh) * 8);
        #pragma unroll
        for (int nj = 0; nj < NI; ++nj)
          acc[p][mi][nj] = __builtin_amdgcn_mfma_f32_16x16x32_bf16(a, bfr[c][nj], acc[p][mi][nj], 0, 0, 0);
      }
    }
  };

  loadB(0, b0);
  __syncthreads();   // A tile ready; only barrier in the kernel

  #pragma unroll
  for (int cc = 0; cc < 16; cc += 2) {
    loadB(cc + 1, b1);
    compute(cc, b0);
    if (cc + 2 < 16) loadB(cc + 2, b0);
    compute(cc + 1, b1);
  }

  // ---- epilogue: C/D row = q*4+r (m), col = li (oc) ----
  if (!FINAL) {
    #pragma unroll
    for (int p = 0; p < 4; ++p) {
      const int py = p >> 1, px = p & 1;
      #pragma unroll
      for (int nj = 0; nj < NI; ++nj) {
        const int oc = n0 + wn * WN + nj * 16 + li;
        const float bv = bias[oc];
        #pragma unroll
        for (int mi = 0; mi < MI; ++mi) {
          #pragma unroll
          for (int r = 0; r < 4; ++r) {
            const int pix = (wm * MI + mi) * 16 + q * 4 + r;
            const int y = tb * ROWS + (pix >> LIW), x = pix & (IW - 1);
            float v = acc[p][mi][nj][r] + bv;
            if (RELU) v = fmaxf(v, 0.f);
            xout[(((size_t)img * OH2 + 2 * y + py + 1) * OW2 + 2 * x + px + 1) * OCp + oc] =
                __float2bfloat16(v);
          }
        }
      }
    }
  } else {
    const int oc = li;  // NI==1, wn==0 for FINAL config
    if (oc < OCr) {
      const float bv = bias[oc];
      #pragma unroll
      for (int py = 0; py < 2; ++py)
        #pragma unroll
        for (int mi = 0; mi < MI; ++mi)
          #pragma unroll
          for (int r = 0; r < 4; ++r) {
            const int pix = (wm * MI + mi) * 16 + q * 4 + r;
            const int y = tb * ROWS + (pix >> LIW), x = pix & (IW - 1);
            float2 v2;
            v2.x = acc[py * 2 + 0][mi][0][r] + bv;
            v2.y = acc[py * 2 + 1][mi][0][r] + bv;
            *(float2*)(&fout[(((size_t)img * 3 + oc) * 64 + 2 * y + py) * 64 + 2 * x]) = v2;
          }
    }
  }
}

// ---------------- launch ----------------
extern "C" void kernel_launch(void* const* d_in, const int* in_sizes, int n_in,
                              void* d_out, int out_size, void* d_ws, size_t ws_size,
                              hipStream_t stream) {
  const float* x  = (const float*)d_in[0];
  const float* gw = (const float*)d_in[1];
  const float* gb = (const float*)d_in[2];
  const float* z  = (const float*)d_in[3];
  const float* w1 = (const float*)d_in[4];
  const float* b1 = (const float*)d_in[5];
  const float* w2 = (const float*)d_in[6];
  const float* b2 = (const float*)d_in[7];
  const float* w3 = (const float*)d_in[8];
  const float* b3 = (const float*)d_in[9];
  float* out = (float*)d_out;

  char* w = (char*)d_ws;
  float* lp  = (float*)(w);
  bf16* x1  = (bf16*)(w + 65536);
  bf16* x2  = (bf16*)(w + 13172736);
  bf16* x3  = (bf16*)(w + 55640064);
  bf16* wt1 = (bf16*)(w + 131399680);
  bf16* wt2 = (bf16*)(w + 131923968);
  bf16* wt3 = (bf16*)(w + 132186112);

  // halo zeroing (borders only)
  zero_halo<<<(512*36*16 + 255) / 256, 256, 0, stream>>>(x1, 8, 8, 128);
  zero_halo<<<(512*68*16 + 255) / 256, 256, 0, stream>>>(x2, 16, 16, 128);
  zero_halo<<<(512*132*8 + 255) / 256, 256, 0, stream>>>(x3, 32, 32, 64);

  // gating -> leaf probabilities
  gate_kernel<<<512, 64, 0, stream>>>(x, gw, gb, lp);

  // weight transforms (fp32 -> chunked bf16 fragment layout)
  wprep_kernel<<<(16*128*128 + 255) / 256, 256, 0, stream>>>(w1, wt1, 128, 128, 128);
  wprep_kernel<<<(16*64*128 + 255) / 256, 256, 0, stream>>>(w2, wt2, 128, 64, 64);
  wprep_kernel<<<(16*16*64 + 255) / 256, 256, 0, stream>>>(w3, wt3, 64, 3, 16);

  // mixture -> x1 interior (NHWC bf16)
  mixture_kernel<<<dim3(64, 8), 256, 0, stream>>>(z, lp, x1);

  // conv1: 128->128, 8x8 -> 16x16, relu. M=64/img, oc split 2. LDS 25.6K, ~160 VGPR -> 3 w/EU
  convt_reg<128,128,128, 8, 8, 8, 64, 2,2, 2,2, 3, true,false>
      <<<dim3(512, 2), 256, 0, stream>>>(x1, wt1, b1, x2, nullptr);
  // conv2: 128->64, 16x16 -> 32x32, relu. ROWS=8 -> M=128, MI=4. LDS 46.1K, ~230 VGPR -> 2 w/EU
  convt_reg<128, 64, 64,16,16, 8, 64, 2,2, 4,2, 2, true,false>
      <<<dim3(1024, 1), 256, 0, stream>>>(x2, wt2, b2, x3, nullptr);
  // conv3: 64->3(pad16), 32x32 -> 64x64, fp32 NCHW out. ROWS=8 -> M=256. LDS 43.5K, ~110 VGPR -> 4 w/EU
  convt_reg< 64, 16,  3,32,32, 8, 16, 4,1, 4,1, 4, false,true>
      <<<dim3(2048, 1), 256, 0, stream>>>(x3, wt3, b3, nullptr, out);
}

// Round 7
// 212.490 us; speedup vs baseline: 1.3755x; 1.3755x over previous
//
#include <hip/hip_runtime.h>
#include <hip/hip_bf16.h>
#include <stdint.h>

using bf16 = __hip_bfloat16;
typedef __attribute__((ext_vector_type(8))) short bf16x8;
typedef __attribute__((ext_vector_type(4))) float f32x4;

#define BATCHN 512

// ================= merged prologue: halo-zero x3, wprep x3, gating =================
__device__ __forceinline__ void zero_halo_dev(bf16* buf, int H, int W, int C, int idx) {
  int nvec = C >> 3;
  int P = 2 * (W + 2) + 2 * H;
  if (idx >= BATCHN * P * nvec) return;
  int cv = idx % nvec;
  int p = (idx / nvec) % P;
  int b = idx / (nvec * P);
  int row, col;
  if (p < W + 2) { row = 0; col = p; }
  else if (p < 2 * (W + 2)) { row = H + 1; col = p - (W + 2); }
  else { int q = p - 2 * (W + 2); row = 1 + (q >> 1); col = (q & 1) ? (W + 1) : 0; }
  float4 z4 = {0.f, 0.f, 0.f, 0.f};
  *(float4*)(buf + ((size_t)(b * (H + 2) + row) * (W + 2) + col) * C + cv * 8) = z4;
}

// wt layout: gB[chunk=(p*4+tap)][c][q][oc(OCp)][e], ic = c*32+q*8+e
__device__ __forceinline__ void wprep_dev(const float* w, bf16* wt, int IC, int OCr, int OCp, int idx) {
  int NC = IC / 32;
  if (idx >= 16 * OCp * IC) return;
  int e = idx & 7;
  int t = idx >> 3;
  int oc = t % OCp; t /= OCp;
  int q = t & 3; t >>= 2;
  int c = t % NC; t /= NC;
  int tap = t & 3, p = t >> 2;
  int ic = c * 32 + q * 8 + e;
  int dy = tap >> 1, dx = tap & 1;
  int py = p >> 1, px = p & 1;
  const int ktab[2][2] = {{1, 3}, {2, 0}};
  int ky = ktab[py][dy], kx = ktab[px][dx];
  float v = 0.f;
  if (oc < OCr) v = w[((ic * OCr + oc) * 4 + ky) * 4 + kx];
  wt[idx] = __float2bfloat16(v);
}

#define NB_Z1 1152   // 512*36*16 /256
#define NB_Z2 2176   // 512*68*16 /256
#define NB_Z3 2112   // 512*132*8 /256
#define NB_W1 1024
#define NB_W2 512
#define NB_W3 64
#define NB_G  128    // 512 images / 4 per block

__global__ void prep_kernel(bf16* x1, bf16* x2, bf16* x3,
                            const float* w1, bf16* wt1, const float* w2, bf16* wt2,
                            const float* w3, bf16* wt3,
                            const float* x, const float* gw, const float* gb, float* lp) {
  int bid = blockIdx.x;
  int tid = threadIdx.x;
  if (bid < NB_Z1) { zero_halo_dev(x1, 8, 8, 128, bid * 256 + tid); return; }
  bid -= NB_Z1;
  if (bid < NB_Z2) { zero_halo_dev(x2, 16, 16, 128, bid * 256 + tid); return; }
  bid -= NB_Z2;
  if (bid < NB_Z3) { zero_halo_dev(x3, 32, 32, 64, bid * 256 + tid); return; }
  bid -= NB_Z3;
  if (bid < NB_W1) { wprep_dev(w1, wt1, 128, 128, 128, bid * 256 + tid); return; }
  bid -= NB_W1;
  if (bid < NB_W2) { wprep_dev(w2, wt2, 128, 64, 64, bid * 256 + tid); return; }
  bid -= NB_W2;
  if (bid < NB_W3) { wprep_dev(w3, wt3, 64, 3, 16, bid * 256 + tid); return; }
  bid -= NB_W3;
  // gating: 4 images per block
  __shared__ float xs[4][128];
  __shared__ float gs[4][32];
  const int sub = tid >> 6, t = tid & 63;
  const int b = bid * 4 + sub;
  xs[sub][t] = x[b * 128 + t];
  xs[sub][t + 64] = x[b * 128 + 64 + t];
  __syncthreads();
  if (t < 31) {
    float acc = gb[t];
    #pragma unroll 8
    for (int k = 0; k < 128; ++k) acc += xs[sub][k] * gw[k * 31 + t];
    gs[sub][t] = 1.f / (1.f + __expf(-acc));
  }
  __syncthreads();
  if (t < 32) {
    float prob = 1.f;
    #pragma unroll
    for (int d = 1; d <= 5; ++d) {
      int i = t >> (6 - d);
      int node = (1 << (d - 1)) - 1 + i;
      float gv = gs[sub][node];
      prob *= ((t >> (5 - d)) & 1) ? (1.f - gv) : gv;
    }
    lp[b * 32 + t] = prob;
  }
}

// ---------------- mixture: out0 = lp @ z.T, written NHWC bf16 into x1 interior ----------------
__global__ void mixture_kernel(const float* __restrict__ z, const float* __restrict__ lp,
                               bf16* __restrict__ x1) {
  __shared__ float lps[64 * 32];
  const int s = blockIdx.x;          // h*8+w
  const int h = s >> 3, w = s & 7;
  const int b0 = blockIdx.y * 64;
  const int t = threadIdx.x;
  const int c = t & 127;
  const int half = t >> 7;
  float4 zr[8];
  const float4* zp = (const float4*)(z + (size_t)(c * 64 + s) * 32);
  #pragma unroll
  for (int i = 0; i < 8; ++i) zr[i] = zp[i];
  #pragma unroll
  for (int i = 0; i < 8; ++i) lps[t + 256 * i] = lp[b0 * 32 + t + 256 * i];
  __syncthreads();
  for (int bs = 0; bs < 32; ++bs) {
    int bl = half * 32 + bs;
    const float4* lr = (const float4*)(lps + bl * 32);
    float acc = 0.f;
    #pragma unroll
    for (int i = 0; i < 8; ++i) {
      float4 l4 = lr[i];
      acc += zr[i].x * l4.x + zr[i].y * l4.y + zr[i].z * l4.z + zr[i].w * l4.w;
    }
    int b = b0 + bl;
    x1[((size_t)(b * 10 + h + 1) * 10 + (w + 1)) * 128 + c] = __float2bfloat16(acc);
  }
}

// ---------------- barrier-free parity-fused transposed conv, register-B depth-2 ----------------
// A: spatial tile staged ONCE into LDS (read-only after one barrier).
// B: fragments loaded global->VGPR, 3-buffer rotation (depth-2 prefetch covers L2 latency).
// acc kept at 64 regs (4 parities x MI x NI x 4) to avoid round-6's spills.
// Light s_barrier every 2 chunks keeps waves convergent (L1 B-sharing, coherent stores).
template<int IC, int OCp, int OCr, int IH, int IW, int ROWS, int BN,
         int WAVES_M, int WAVES_N, int MI, int NI, bool RELU, bool FINAL>
__global__ __launch_bounds__(256, 2)
void convt_reg(const bf16* __restrict__ xin, const bf16* __restrict__ wt,
               const float* __restrict__ bias, bf16* __restrict__ xout,
               float* __restrict__ fout) {
  constexpr int NC = IC / 32;
  constexpr int PLANES = NC * 4;
  constexpr int IH2 = IH + 2, IW2 = IW + 2;
  constexpr int OH2 = 2 * IH + 2, OW2 = 2 * IW + 2;
  constexpr int NPIX = (ROWS + 2) * IW2;
  constexpr int BPI = IH / ROWS;
  constexpr int WM = MI * 16, WN = NI * 16;
  constexpr int LIW = (IW == 8 ? 3 : (IW == 16 ? 4 : 5));
  constexpr int ICV = IC / 8;
  __shared__ bf16 Alds[PLANES * NPIX * 8];

  const int tid = threadIdx.x;
  const int wave = tid >> 6, lane = tid & 63;
  const int q = lane >> 4, li = lane & 15;
  const int wm = wave / WAVES_N, wn = wave % WAVES_N;
  const int img = blockIdx.x / BPI;
  const int tb = blockIdx.x % BPI;
  const int n0 = blockIdx.y * BN;

  // ---- stage A tile: global [pix][ic] -> LDS [plane=c*4+q][pix][8] ----
  const bf16* src = xin + ((size_t)img * IH2 + tb * ROWS) * IW2 * IC;
  for (int g = tid; g < NPIX * ICV; g += 256) {
    const int pix = g / ICV;
    const int gr = g % ICV;
    const float4 v = *(const float4*)(src + (size_t)g * 8);
    *(float4*)(&Alds[(gr * NPIX + pix) * 8]) = v;
  }

  // per-lane B base pointer: column = n0 + wn*WN + li (+ nj*16 in offset)
  const bf16* wtp = wt + (size_t)(n0 + wn * WN + li) * 8;

  // per-mi center pixel (lane li = m-row within 16)
  int cpix[MI];
  #pragma unroll
  for (int mi = 0; mi < MI; ++mi) {
    const int m = wm * WM + mi * 16 + li;
    cpix[mi] = ((m >> LIW) + 1) * IW2 + (m & (IW - 1)) + 1;
  }

  f32x4 acc[4][MI][NI];
  #pragma unroll
  for (int p = 0; p < 4; ++p)
    #pragma unroll
    for (int mi = 0; mi < MI; ++mi)
      #pragma unroll
      for (int nj = 0; nj < NI; ++nj)
        acc[p][mi][nj] = (f32x4){0.f, 0.f, 0.f, 0.f};

  bf16x8 bb[3][NC][NI];

  auto loadB = [&](int chunk, int buf) {
    #pragma unroll
    for (int c = 0; c < NC; ++c)
      #pragma unroll
      for (int nj = 0; nj < NI; ++nj)
        bb[buf][c][nj] = *(const bf16x8*)(wtp + ((size_t)(chunk * PLANES + c * 4 + q) * OCp + nj * 16) * 8);
  };
  auto compute = [&](int chunk, int buf) {
    const int p = chunk >> 2, tap = chunk & 3;
    const int py = p >> 1, px = p & 1;
    const int sh = ((tap >> 1) ? (py ? 1 : -1) * IW2 : 0) + ((tap & 1) ? (px ? 1 : -1) : 0);
    #pragma unroll
    for (int c = 0; c < NC; ++c) {
      #pragma unroll
      for (int mi = 0; mi < MI; ++mi) {
        const bf16x8 a = *(const bf16x8*)(Alds + ((c * 4 + q) * NPIX + cpix[mi] + sh) * 8);
        #pragma unroll
        for (int nj = 0; nj < NI; ++nj)
          acc[p][mi][nj] = __builtin_amdgcn_mfma_f32_16x16x32_bf16(a, bb[buf][c][nj], acc[p][mi][nj], 0, 0, 0);
      }
    }
  };

  loadB(0, 0);
  loadB(1, 1);
  __syncthreads();   // A tile ready; only full barrier in the kernel

  #pragma unroll
  for (int cc = 0; cc < 16; ++cc) {
    if (cc + 2 < 16) loadB(cc + 2, (cc + 2) % 3);
    compute(cc, cc % 3);
    if ((cc & 1) && cc < 15) __builtin_amdgcn_s_barrier();  // light convergence, no drain
  }

  // ---- epilogue: C/D row = q*4+r (m), col = li (oc) ----
  if (!FINAL) {
    #pragma unroll
    for (int p = 0; p < 4; ++p) {
      const int py = p >> 1, px = p & 1;
      #pragma unroll
      for (int nj = 0; nj < NI; ++nj) {
        const int oc = n0 + wn * WN + nj * 16 + li;
        const float bv = bias[oc];
        #pragma unroll
        for (int mi = 0; mi < MI; ++mi) {
          #pragma unroll
          for (int r = 0; r < 4; ++r) {
            const int pix = (wm * MI + mi) * 16 + q * 4 + r;
            const int y = tb * ROWS + (pix >> LIW), x = pix & (IW - 1);
            float v = acc[p][mi][nj][r] + bv;
            if (RELU) v = fmaxf(v, 0.f);
            xout[(((size_t)img * OH2 + 2 * y + py + 1) * OW2 + 2 * x + px + 1) * OCp + oc] =
                __float2bfloat16(v);
          }
        }
      }
    }
  } else {
    const int oc = li;  // NI==1, wn==0 for FINAL config
    if (oc < OCr) {
      const float bv = bias[oc];
      #pragma unroll
      for (int py = 0; py < 2; ++py)
        #pragma unroll
        for (int mi = 0; mi < MI; ++mi)
          #pragma unroll
          for (int r = 0; r < 4; ++r) {
            const int pix = (wm * MI + mi) * 16 + q * 4 + r;
            const int y = tb * ROWS + (pix >> LIW), x = pix & (IW - 1);
            float2 v2;
            v2.x = acc[py * 2 + 0][mi][0][r] + bv;
            v2.y = acc[py * 2 + 1][mi][0][r] + bv;
            *(float2*)(&fout[(((size_t)img * 3 + oc) * 64 + 2 * y + py) * 64 + 2 * x]) = v2;
          }
    }
  }
}

// ---------------- launch ----------------
extern "C" void kernel_launch(void* const* d_in, const int* in_sizes, int n_in,
                              void* d_out, int out_size, void* d_ws, size_t ws_size,
                              hipStream_t stream) {
  const float* x  = (const float*)d_in[0];
  const float* gw = (const float*)d_in[1];
  const float* gb = (const float*)d_in[2];
  const float* z  = (const float*)d_in[3];
  const float* w1 = (const float*)d_in[4];
  const float* b1 = (const float*)d_in[5];
  const float* w2 = (const float*)d_in[6];
  const float* b2 = (const float*)d_in[7];
  const float* w3 = (const float*)d_in[8];
  const float* b3 = (const float*)d_in[9];
  float* out = (float*)d_out;

  char* w = (char*)d_ws;
  float* lp  = (float*)(w);
  bf16* x1  = (bf16*)(w + 65536);
  bf16* x2  = (bf16*)(w + 13172736);
  bf16* x3  = (bf16*)(w + 55640064);
  bf16* wt1 = (bf16*)(w + 131399680);
  bf16* wt2 = (bf16*)(w + 131923968);
  bf16* wt3 = (bf16*)(w + 132186112);

  // merged prologue: halo zeroing + weight transforms + gating
  prep_kernel<<<NB_Z1 + NB_Z2 + NB_Z3 + NB_W1 + NB_W2 + NB_W3 + NB_G, 256, 0, stream>>>(
      x1, x2, x3, w1, wt1, w2, wt2, w3, wt3, x, gw, gb, lp);

  // mixture -> x1 interior (NHWC bf16)
  mixture_kernel<<<dim3(64, 8), 256, 0, stream>>>(z, lp, x1);

  // conv1: 128->128, 8x8 -> 16x16, relu. M=64/img, oc split 2. acc=64, bb=96 -> no spill
  convt_reg<128,128,128, 8, 8, 8, 64, 2,2, 2,2, true,false>
      <<<dim3(512, 2), 256, 0, stream>>>(x1, wt1, b1, x2, nullptr);
  // conv2: 128->64, 16x16 -> 32x32, relu. ROWS=4 -> M=64, MI=2,NI=2. 2048 blocks
  convt_reg<128, 64, 64,16,16, 4, 64, 2,2, 2,2, true,false>
      <<<dim3(2048, 1), 256, 0, stream>>>(x2, wt2, b2, x3, nullptr);
  // conv3: 64->3(pad16), 32x32 -> 64x64, fp32 NCHW out. ROWS=8 -> M=256, MI=4,NI=1
  convt_reg< 64, 16,  3,32,32, 8, 16, 4,1, 4,1, false,true>
      <<<dim3(2048, 1), 256, 0, stream>>>(x3, wt3, b3, nullptr, out);
}